// Round 3
// baseline (266.731 us; speedup 1.0000x reference)
//
#include <hip/hip_runtime.h>

// OctreeDWConv: out[i,c] = sum_k (neigh[i,k]>=0 ? data[neigh[i,k],c] : 0) * w[k,c]
// N=200000, K=27, C=64, fp32 in/out.
//
// Layout: 16 lanes per row (each lane owns 4 channels as v4f) -> every
// gather of data[n,:] is a contiguous 256B segment, 16B/lane coalesced.
// Block(256) = 16 rows. Neigh indices staged via LDS (kills the 16x-redundant
// per-lane index loads). Gathers issued in explicit batches of 9 to force
// memory-level parallelism. Nontemporal store for write-once output.

typedef float v4f __attribute__((ext_vector_type(4)));

constexpr int K   = 27;
constexpr int C   = 64;
constexpr int C4  = C / 4;           // 16 v4f per row
constexpr int RPB = 16;              // rows per block
constexpr int NB  = 9;               // gather batch size (27 = 3*9)

__global__ __launch_bounds__(256) void octree_dwconv_kernel(
    const v4f* __restrict__ data4,
    const v4f* __restrict__ weights4,
    const int* __restrict__ neigh,
    v4f*       __restrict__ out4,
    int nrows)
{
    __shared__ v4f w_lds[K * C4];   // 6912 B
    __shared__ int n_lds[RPB * K];  // 1728 B

    const int tid = threadIdx.x;

    // Stage weights (432 v4f) and this block's neigh rows (432 ints).
    for (int idx = tid; idx < K * C4; idx += 256)
        w_lds[idx] = weights4[idx];

    const long nbase = (long)blockIdx.x * RPB * K;
    const long ntot  = (long)nrows * K;
    for (int idx = tid; idx < RPB * K; idx += 256) {
        const long g = nbase + idx;
        n_lds[idx] = (g < ntot) ? __builtin_nontemporal_load(neigh + g) : -1;
    }
    __syncthreads();

    const int l     = tid & (C4 - 1);
    const int group = tid >> 4;
    const int row   = blockIdx.x * RPB + group;
    if (row >= nrows) return;

    const int* __restrict__ nrow = n_lds + group * K;  // broadcast reads

    v4f acc = (v4f){0.f, 0.f, 0.f, 0.f};

    #pragma unroll
    for (int b = 0; b < K; b += NB) {
        int nk[NB];
        v4f d[NB];
        #pragma unroll
        for (int j = 0; j < NB; ++j) nk[j] = nrow[b + j];
        // Issue all 9 gathers back-to-back (in flight together).
        #pragma unroll
        for (int j = 0; j < NB; ++j) {
            const int n = nk[j];
            d[j] = data4[(n < 0 ? 0 : n) * C4 + l];
        }
        // Consume: mask invalid, FMA against LDS weights.
        #pragma unroll
        for (int j = 0; j < NB; ++j) {
            if (nk[j] < 0) d[j] = (v4f){0.f, 0.f, 0.f, 0.f};
            const v4f w = w_lds[(b + j) * C4 + l];
            acc += d[j] * w;
        }
    }

    __builtin_nontemporal_store(acc, out4 + row * C4 + l);  // write-once
}

extern "C" void kernel_launch(void* const* d_in, const int* in_sizes, int n_in,
                              void* d_out, int out_size, void* d_ws, size_t ws_size,
                              hipStream_t stream) {
    const v4f* data4    = (const v4f*)d_in[0];
    const v4f* weights4 = (const v4f*)d_in[1];
    const int* neigh    = (const int*)d_in[2];
    v4f*       out4     = (v4f*)d_out;

    const int nrows  = in_sizes[0] / C;             // 200000
    const int blocks = (nrows + RPB - 1) / RPB;     // 12500

    octree_dwconv_kernel<<<blocks, 256, 0, stream>>>(data4, weights4, neigh, out4, nrows);
}

// Round 4
// 201.944 us; speedup vs baseline: 1.3208x; 1.3208x over previous
//
#include <hip/hip_runtime.h>
#include <stdint.h>

// OctreeDWConv: out[i,c] = sum_k (neigh[i,k]>=0 ? data[neigh[i,k],c] : 0) * w[k,c]
// N=200000, K=27, C=64, fp32 in/out.
//
// Round-3 model: gather is bound by per-CU outstanding-miss slots x latency,
// i.e. by the COUNT of 64B lines gathered (21.6M). Strategy: compact data to
// bf16 (RNE) in d_ws first -> each gathered row is 128B = 2 lines instead of
// 4 -> halve the line count. fp32 weights + fp32 accumulation.
//
// Gather layout: 8 lanes per row, each lane owns 8 channels as one 16B
// uint32x4 load (8 bf16). Block(256) = 32 rows, grid = 6250 exact.

typedef float    v4f __attribute__((ext_vector_type(4)));
typedef uint32_t v4u __attribute__((ext_vector_type(4)));

constexpr int K   = 27;
constexpr int C   = 64;
constexpr int RPB = 32;              // rows per block (8 lanes/row)

__device__ inline uint32_t bf16pack(float lo, float hi) {
    // round-to-nearest-even bf16, packed (lo in bits 0..15, hi in 16..31)
    uint32_t a = __float_as_uint(lo);
    uint32_t b = __float_as_uint(hi);
    a = (a + 0x7FFFu + ((a >> 16) & 1u)) >> 16;
    b = (b + 0x7FFFu + ((b >> 16) & 1u)) & 0xFFFF0000u;
    return a | b;
}

__global__ __launch_bounds__(256) void convert_kernel(
    const v4f* __restrict__ in,     // fp32 data, 2 x v4f per thread
    v4u*       __restrict__ outq,   // packed bf16, 1 x v4u per thread
    int n8)                         // N*C/8
{
    const int i = blockIdx.x * 256 + threadIdx.x;
    if (i >= n8) return;
    // nontemporal read: fp32 data is read exactly once, keep L2 for bf16 copy
    v4f a = __builtin_nontemporal_load(in + 2 * i);
    v4f b = __builtin_nontemporal_load(in + 2 * i + 1);
    v4u q;
    q.x = bf16pack(a.x, a.y);
    q.y = bf16pack(a.z, a.w);
    q.z = bf16pack(b.x, b.y);
    q.w = bf16pack(b.z, b.w);
    outq[i] = q;                    // cached store: warm L2 for the gather
}

__global__ __launch_bounds__(256) void gather_kernel(
    const v4u*   __restrict__ dataq,   // [N*8] packed bf16 rows (128B/row)
    const float* __restrict__ weights, // [K*C] fp32
    const int*   __restrict__ neigh,   // [N*K]
    v4f*         __restrict__ out4,    // [N*16] fp32
    int nrows)
{
    __shared__ float w_lds[K * C];     // 6912 B
    __shared__ int   n_lds[RPB * K];   // 3456 B

    const int tid = threadIdx.x;
    for (int idx = tid; idx < K * C / 4; idx += 256)
        ((v4f*)w_lds)[idx] = ((const v4f*)weights)[idx];

    const long nbase = (long)blockIdx.x * RPB * K;
    const long ntot  = (long)nrows * K;
    for (int idx = tid; idx < RPB * K; idx += 256) {
        const long g = nbase + idx;
        n_lds[idx] = (g < ntot) ? __builtin_nontemporal_load(neigh + g) : -1;
    }
    __syncthreads();

    const int l     = tid & 7;         // lane-in-row: channels 8l..8l+7
    const int group = tid >> 3;        // 0..31
    const int row   = blockIdx.x * RPB + group;
    if (row >= nrows) return;

    const int* __restrict__ nrow = n_lds + group * K;

    v4f acc0 = (v4f){0.f, 0.f, 0.f, 0.f};
    v4f acc1 = (v4f){0.f, 0.f, 0.f, 0.f};

    #pragma unroll
    for (int b = 0; b < K; b += 9) {
        int nk[9];
        v4u d[9];
        #pragma unroll
        for (int j = 0; j < 9; ++j) nk[j] = nrow[b + j];
        #pragma unroll
        for (int j = 0; j < 9; ++j) {
            const int n = nk[j];
            d[j] = dataq[(n < 0 ? 0 : n) * 8 + l];   // 128B/row gather, 2 lines
        }
        #pragma unroll
        for (int j = 0; j < 9; ++j) {
            if (nk[j] < 0) d[j] = (v4u){0u, 0u, 0u, 0u};
            const int k = b + j;
            const v4f* wv = (const v4f*)(w_lds + k * C + l * 8);
            const v4f w0 = wv[0];
            const v4f w1 = wv[1];
            // bf16 -> fp32 is a shift/mask; fp32 FMA into acc
            acc0.x += __uint_as_float(d[j].x << 16)          * w0.x;
            acc0.y += __uint_as_float(d[j].x & 0xFFFF0000u)  * w0.y;
            acc0.z += __uint_as_float(d[j].y << 16)          * w0.z;
            acc0.w += __uint_as_float(d[j].y & 0xFFFF0000u)  * w0.w;
            acc1.x += __uint_as_float(d[j].z << 16)          * w1.x;
            acc1.y += __uint_as_float(d[j].z & 0xFFFF0000u)  * w1.y;
            acc1.z += __uint_as_float(d[j].w << 16)          * w1.z;
            acc1.w += __uint_as_float(d[j].w & 0xFFFF0000u)  * w1.w;
        }
    }

    v4f* o = out4 + row * (C / 4) + l * 2;
    __builtin_nontemporal_store(acc0, o);
    __builtin_nontemporal_store(acc1, o + 1);
}

extern "C" void kernel_launch(void* const* d_in, const int* in_sizes, int n_in,
                              void* d_out, int out_size, void* d_ws, size_t ws_size,
                              hipStream_t stream) {
    const float* data    = (const float*)d_in[0];   // [N, C] fp32
    const float* weights = (const float*)d_in[1];   // [K, 1, C] fp32
    const int*   neigh   = (const int*)d_in[2];     // [N, K] int32
    v4f*         out4    = (v4f*)d_out;
    v4u*         dataq   = (v4u*)d_ws;              // needs N*C*2 = 25.6 MB

    const int nrows = in_sizes[0] / C;              // 200000
    const int n8    = nrows * C / 8;                // 1.6M

    convert_kernel<<<(n8 + 255) / 256, 256, 0, stream>>>(
        (const v4f*)data, dataq, n8);

    const int blocks = (nrows + RPB - 1) / RPB;     // 6250
    gather_kernel<<<blocks, 256, 0, stream>>>(
        dataq, weights, neigh, out4, nrows);
}